// Round 7
// baseline (162.907 us; speedup 1.0000x reference)
//
#include <hip/hip_runtime.h>
#include <hip/hip_bf16.h>

// TT linear: y[b, o01*64+o23] = sum_{r2} (U_{r2}^T @ X_b @ V_{r2})[o01][o23]
//   U_{r2}[i01][o01] = sum_{r1} c0[0,i0,o0,r1] c1[r1,i1,o1,r2]
//   V_{r2}[i23][o23] = sum_{r3} c2[r2,i2,o2,r3] c3[r3,i3,o3,0]
// Per wave (one batch row): GEMM1 S = X*V_{r2}, in-register relayout via
// v_permlane32_swap, GEMM2 Y += U^T*S.  Weights pre-packed in 32x32x16 MFMA
// fragment order in d_ws; each r2's 16 KB weight slice is staged block-wide
// into LDS with global_load_lds (double-buffered, 1 barrier/iter) so the
// per-wave weight-load latency that dominated round 5 is hidden under compute.

typedef __attribute__((ext_vector_type(8))) short bf16x8;    // 8 bf16 = 4 VGPRs
typedef __attribute__((ext_vector_type(16))) float f32x16;   // 32x32 MFMA acc

#define MFMA32(a, b, c) __builtin_amdgcn_mfma_f32_32x32x16_bf16(a, b, c, 0, 0, 0)

__device__ __forceinline__ unsigned short bfu(float f) {
    __hip_bfloat16 h = __float2bfloat16(f);                   // RNE
    return *reinterpret_cast<unsigned short*>(&h);
}
__device__ __forceinline__ unsigned pk2(float a, float b) {
    return (unsigned)bfu(a) | ((unsigned)bfu(b) << 16);
}

__device__ __forceinline__ void gload_lds16(const char* g, char* l) {
    __builtin_amdgcn_global_load_lds(
        (const __attribute__((address_space(1))) unsigned int*)g,
        (__attribute__((address_space(3))) unsigned int*)l,
        16, 0, 0);                                            // 16B/lane, wave-linear LDS dest
}

// ---------------------------------------------------------------------------
// Prep: contract cores, write bf16 packed in 32x32x16 MFMA fragment order.
// First 32768 (64 KB): V B-frags [r2][nt][ks1][lane][j]:
//   k=i23=ks1*16+(lane>>5)*8+j, n=o23=nt*32+(lane&31)
// Next 32768 (64 KB): U A-frags [r2][mt2][kt][ks2][lane][j]:
//   k=i01=kt*32+ks2*16+(lane>>5)*8+j, m=o01=mt2*32+(lane&31)
// ---------------------------------------------------------------------------
__global__ void tt_prep(const float* __restrict__ c0, const float* __restrict__ c1,
                        const float* __restrict__ c2, const float* __restrict__ c3,
                        unsigned short* __restrict__ wpack) {
    int e    = blockIdx.x * 256 + threadIdx.x;                // 0..65535
    int lane = (e >> 3) & 63;
    int j    = e & 7;
    int hi   = lane >> 5, l31 = lane & 31;
    float acc = 0.f;
    if (e < 32768) {
        int idx = e;
        int r2  = idx >> 12;
        int nt  = (idx >> 11) & 1;
        int ks1 = (idx >> 9) & 3;
        int i23 = ks1 * 16 + hi * 8 + j;
        int o23 = nt * 32 + l31;
        int i2 = i23 >> 3, i3 = i23 & 7, o2 = o23 >> 3, o3 = o23 & 7;
        #pragma unroll
        for (int r3 = 0; r3 < 8; ++r3)
            acc += c2[((r2 * 8 + i2) * 8 + o2) * 8 + r3] * c3[(r3 * 8 + i3) * 8 + o3];
    } else {
        int idx = e - 32768;
        int r2  = idx >> 12;
        int mt2 = (idx >> 11) & 1;
        int kt  = (idx >> 10) & 1;
        int ks2 = (idx >> 9) & 1;
        int i01 = kt * 32 + ks2 * 16 + hi * 8 + j;
        int o01 = mt2 * 32 + l31;
        int i0 = i01 >> 3, i1 = i01 & 7, o0 = o01 >> 3, o1 = o01 & 7;
        #pragma unroll
        for (int r1 = 0; r1 < 8; ++r1)
            acc += c0[(i0 * 8 + o0) * 8 + r1] * c1[((r1 * 8 + i1) * 8 + o1) * 8 + r2];
    }
    wpack[e] = bfu(acc);
}

// ---------------------------------------------------------------------------
// Stage one r2 weight slice (16 KB: V frags 0-7 at +0, U frags 0-7 at +8192)
// into LDS. 16 global_load_lds across the block: wave 0 -> V frags 0-3,
// wave 1 -> V 4-7, wave 2 -> U 0-3, wave 3 -> U 4-7.
// ---------------------------------------------------------------------------
__device__ __forceinline__ void stage_r2(const char* wp, char* sm, int r2,
                                         int wave, int lane) {
    int isU = wave >> 1;
    int f0  = (wave & 1) * 4;
    const char* src = wp + isU * 65536 + (r2 * 8 + f0) * 1024 + lane * 16;
    char* dst = sm + isU * 8192 + f0 * 1024;                  // wave-uniform
    #pragma unroll
    for (int i = 0; i < 4; ++i)
        gload_lds16(src + i * 1024, dst + i * 1024);
}

// ---------------------------------------------------------------------------
// Main: 1024 blocks x 256 threads (4 waves). Wave w of block g: row b = g*4+w.
// ---------------------------------------------------------------------------
__global__ __launch_bounds__(256, 3)
void tt_main(const float* __restrict__ x, const float* __restrict__ bias,
             const unsigned short* __restrict__ wpack, float* __restrict__ out) {
    __shared__ __attribute__((aligned(16))) char smem[2][16384];
    const int lane = threadIdx.x & 63;
    const int wave = threadIdx.x >> 6;
    const int b    = blockIdx.x * 4 + wave;
    const int l31  = lane & 31;
    const int hi   = lane >> 5;
    const char* wp = (const char*)wpack;

    // ---- stage r2=0 while we load/convert x ----
    stage_r2(wp, smem[0], 0, wave, lane);

    // ---- x A-frags: xa[mt][ks1], a[j] = x[i01=mt*32+l31][i23=ks1*16+hi*8+j] ----
    const float* xb = x + (size_t)b * 4096;
    bf16x8 xa[2][4];
    #pragma unroll
    for (int mt = 0; mt < 2; ++mt)
        #pragma unroll
        for (int ks1 = 0; ks1 < 4; ++ks1) {
            const float* p = xb + (mt * 32 + l31) * 64 + ks1 * 16 + hi * 8;
            float4 u0 = *(const float4*)p;
            float4 u1 = *(const float4*)(p + 4);
            union { unsigned w[4]; bf16x8 v; } t;
            t.w[0] = pk2(u0.x, u0.y);
            t.w[1] = pk2(u0.z, u0.w);
            t.w[2] = pk2(u1.x, u1.y);
            t.w[3] = pk2(u1.z, u1.w);
            xa[mt][ks1] = t.v;
        }

    f32x16 yacc[2][2];
    #pragma unroll
    for (int i = 0; i < 2; ++i)
        #pragma unroll
        for (int k = 0; k < 2; ++k)
            yacc[i][k] = (f32x16)0.0f;

    __syncthreads();                                          // r2=0 staged

    #pragma unroll
    for (int r2 = 0; r2 < 8; ++r2) {
        const char* cur = smem[r2 & 1];
        char*       nxt = smem[(r2 & 1) ^ 1];
        if (r2 < 7)
            stage_r2(wp, nxt, r2 + 1, wave, lane);            // issue-early (T14)

        const char* vb = cur + lane * 16;                     // V frag (nt*4+ks1)<<10
        const char* ub = cur + 8192 + lane * 16;              // U frag ((mt2*2+kt)*2+ks2)<<10

        #pragma unroll
        for (int mt = 0; mt < 2; ++mt) {
            bf16x8 uf[2][2];                                  // [mt2][ks2], kt = mt
            #pragma unroll
            for (int mt2 = 0; mt2 < 2; ++mt2)
                #pragma unroll
                for (int ks2 = 0; ks2 < 2; ++ks2)
                    uf[mt2][ks2] = *(const bf16x8*)(ub + (((mt2 * 2 + mt) * 2 + ks2) << 10));

            #pragma unroll
            for (int nt = 0; nt < 2; ++nt) {
                // GEMM1: S tile (mt,nt) = X * V_{r2}
                f32x16 s = (f32x16)0.0f;
                #pragma unroll
                for (int ks1 = 0; ks1 < 4; ++ks1)
                    s = MFMA32(xa[mt][ks1],
                               *(const bf16x8*)(vb + ((nt * 4 + ks1) << 10)), s);

                // D-layout (4-row groups / half-wave) -> B-frag (8-row groups):
                // (w0,w2)=swap(pk(d0,d1),pk(d4,d5)); (w1,w3)=swap(pk(d2,d3),pk(d6,d7)).
                bf16x8 bf[2];
                #pragma unroll
                for (int ks2 = 0; ks2 < 2; ++ks2) {
                    unsigned A0 = pk2(s[8 * ks2 + 0], s[8 * ks2 + 1]);
                    unsigned B0 = pk2(s[8 * ks2 + 2], s[8 * ks2 + 3]);
                    unsigned A1 = pk2(s[8 * ks2 + 4], s[8 * ks2 + 5]);
                    unsigned B1 = pk2(s[8 * ks2 + 6], s[8 * ks2 + 7]);
                    auto rA = __builtin_amdgcn_permlane32_swap((int)A0, (int)A1, false, false);
                    auto rB = __builtin_amdgcn_permlane32_swap((int)B0, (int)B1, false, false);
                    union { unsigned w[4]; bf16x8 v; } t;
                    t.w[0] = (unsigned)rA[0];
                    t.w[1] = (unsigned)rB[0];
                    t.w[2] = (unsigned)rA[1];
                    t.w[3] = (unsigned)rB[1];
                    bf[ks2] = t.v;
                }

                // GEMM2: Y[mt2][nt] += U^T frag (kt=mt) * S frag
                #pragma unroll
                for (int mt2 = 0; mt2 < 2; ++mt2)
                    #pragma unroll
                    for (int ks2 = 0; ks2 < 2; ++ks2)
                        yacc[mt2][nt] = MFMA32(uf[mt2][ks2], bf[ks2], yacc[mt2][nt]);
            }
        }
        __syncthreads();   // drains stage loads (nxt ready) + all waves done with cur
    }

    // Epilogue: D layout row = (r&3)+8*(r>>2)+4*hi (+32*mt2), col = l31 (+32*nt)
    float* ob = out + (size_t)b * 4096;
    #pragma unroll
    for (int mt2 = 0; mt2 < 2; ++mt2)
        #pragma unroll
        for (int nt = 0; nt < 2; ++nt)
            #pragma unroll
            for (int r = 0; r < 16; ++r) {
                int o01 = mt2 * 32 + (r & 3) + 8 * (r >> 2) + 4 * hi;
                int o23 = nt * 32 + l31;
                int off = o01 * 64 + o23;
                ob[off] = yacc[mt2][nt][r] + bias[off];
            }
}

extern "C" void kernel_launch(void* const* d_in, const int* in_sizes, int n_in,
                              void* d_out, int out_size, void* d_ws, size_t ws_size,
                              hipStream_t stream) {
    const float* x    = (const float*)d_in[0];
    const float* c0   = (const float*)d_in[1];
    const float* c1   = (const float*)d_in[2];
    const float* c2   = (const float*)d_in[3];
    const float* c3   = (const float*)d_in[4];
    const float* bias = (const float*)d_in[5];
    unsigned short* wpack = (unsigned short*)d_ws;             // 64K bf16 = 128 KB

    tt_prep<<<256, 256, 0, stream>>>(c0, c1, c2, c3, wpack);
    tt_main<<<1024, 256, 0, stream>>>(x, bias, wpack, (float*)d_out);
}

// Round 8
// 148.140 us; speedup vs baseline: 1.0997x; 1.0997x over previous
//
#include <hip/hip_runtime.h>
#include <hip/hip_bf16.h>

// TT linear: y[b, o01*64+o23] = sum_{r2} (U_{r2}^T @ X_b @ V_{r2})[o01][o23]
//   U_{r2}[i01][o01] = sum_{r1} c0[0,i0,o0,r1] c1[r1,i1,o1,r2]
//   V_{r2}[i23][o23] = sum_{r3} c2[r2,i2,o2,r3] c3[r3,i3,o3,0]
// Per wave (one batch row): GEMM1 S = X*V_{r2}, in-register relayout via
// v_permlane32_swap, GEMM2 Y += U^T*S. No LDS, no barriers (round-7 showed
// block-synchronized staging regresses). r2 loop fully unrolled with a
// register double-buffer prefetch of V fragments (next r2's V loads issue
// before current r2's compute), removing the per-iteration L2 stall that
// bounded round 5.

typedef __attribute__((ext_vector_type(8))) short bf16x8;    // 8 bf16 = 4 VGPRs
typedef __attribute__((ext_vector_type(16))) float f32x16;   // 32x32 MFMA acc

#define MFMA32(a, b, c) __builtin_amdgcn_mfma_f32_32x32x16_bf16(a, b, c, 0, 0, 0)

__device__ __forceinline__ unsigned short bfu(float f) {
    __hip_bfloat16 h = __float2bfloat16(f);                   // RNE
    return *reinterpret_cast<unsigned short*>(&h);
}
__device__ __forceinline__ unsigned pk2(float a, float b) {
    return (unsigned)bfu(a) | ((unsigned)bfu(b) << 16);
}

// ---------------------------------------------------------------------------
// Prep: contract cores, write bf16 packed in 32x32x16 MFMA fragment order.
// First 32768: V B-frags [r2][nt][ks1][lane][j]:  k=i23=ks1*16+(lane>>5)*8+j, n=o23=nt*32+(lane&31)
// Next  32768: U A-frags [r2][mt2][kt][ks2][lane][j]: k=i01=kt*32+ks2*16+(lane>>5)*8+j, m=o01=mt2*32+(lane&31)
// ---------------------------------------------------------------------------
__global__ void tt_prep(const float* __restrict__ c0, const float* __restrict__ c1,
                        const float* __restrict__ c2, const float* __restrict__ c3,
                        unsigned short* __restrict__ wpack) {
    int e    = blockIdx.x * 256 + threadIdx.x;                // 0..65535
    int lane = (e >> 3) & 63;
    int j    = e & 7;
    int hi   = lane >> 5, l31 = lane & 31;
    float acc = 0.f;
    if (e < 32768) {
        int idx = e;
        int r2  = idx >> 12;
        int nt  = (idx >> 11) & 1;
        int ks1 = (idx >> 9) & 3;
        int i23 = ks1 * 16 + hi * 8 + j;
        int o23 = nt * 32 + l31;
        int i2 = i23 >> 3, i3 = i23 & 7, o2 = o23 >> 3, o3 = o23 & 7;
        #pragma unroll
        for (int r3 = 0; r3 < 8; ++r3)
            acc += c2[((r2 * 8 + i2) * 8 + o2) * 8 + r3] * c3[(r3 * 8 + i3) * 8 + o3];
    } else {
        int idx = e - 32768;
        int r2  = idx >> 12;
        int mt2 = (idx >> 11) & 1;
        int kt  = (idx >> 10) & 1;
        int ks2 = (idx >> 9) & 1;
        int i01 = kt * 32 + ks2 * 16 + hi * 8 + j;
        int o01 = mt2 * 32 + l31;
        int i0 = i01 >> 3, i1 = i01 & 7, o0 = o01 >> 3, o1 = o01 & 7;
        #pragma unroll
        for (int r1 = 0; r1 < 8; ++r1)
            acc += c0[(i0 * 8 + o0) * 8 + r1] * c1[((r1 * 8 + i1) * 8 + o1) * 8 + r2];
    }
    wpack[e] = bfu(acc);
}

// ---------------------------------------------------------------------------
// Main: 1024 blocks x 256 threads (4 waves). Wave w of block g: row b = g*4+w.
// ---------------------------------------------------------------------------
__global__ __launch_bounds__(256, 2)
void tt_main(const float* __restrict__ x, const float* __restrict__ bias,
             const unsigned short* __restrict__ wpack, float* __restrict__ out) {
    const int lane = threadIdx.x & 63;
    const int wave = threadIdx.x >> 6;
    const int b    = blockIdx.x * 4 + wave;
    const int l31  = lane & 31;
    const int hi   = lane >> 5;

    const float* xb = x + (size_t)b * 4096;

    // ---- x A-frags: xa[mt][ks1], a[j] = x[i01=mt*32+l31][i23=ks1*16+hi*8+j] ----
    bf16x8 xa[2][4];
    #pragma unroll
    for (int mt = 0; mt < 2; ++mt)
        #pragma unroll
        for (int ks1 = 0; ks1 < 4; ++ks1) {
            const float* p = xb + (mt * 32 + l31) * 64 + ks1 * 16 + hi * 8;
            float4 u0 = *(const float4*)p;
            float4 u1 = *(const float4*)(p + 4);
            union { unsigned w[4]; bf16x8 v; } t;
            t.w[0] = pk2(u0.x, u0.y);
            t.w[1] = pk2(u0.z, u0.w);
            t.w[2] = pk2(u1.x, u1.y);
            t.w[3] = pk2(u1.z, u1.w);
            xa[mt][ks1] = t.v;
        }

    f32x16 yacc[2][2];
    #pragma unroll
    for (int i = 0; i < 2; ++i)
        #pragma unroll
        for (int k = 0; k < 2; ++k)
            yacc[i][k] = (f32x16)0.0f;

    const bf16x8* Vp = (const bf16x8*)wpack;                       // [r2][nt][ks1][lane]
    const bf16x8* Up = (const bf16x8*)(wpack + 32768);             // [r2][mt2][kt][ks2][lane]

    // ---- V-fragment register double-buffer: prologue loads r2=0 ----
    bf16x8 vfb[2][2][4];                                           // [buf][nt][ks1]
    #pragma unroll
    for (int nt = 0; nt < 2; ++nt)
        #pragma unroll
        for (int ks1 = 0; ks1 < 4; ++ks1)
            vfb[0][nt][ks1] = Vp[(nt * 4 + ks1) * 64 + lane];

    #pragma unroll
    for (int r2 = 0; r2 < 8; ++r2) {
        const int cur = r2 & 1;
        const int nxt = cur ^ 1;

        // Prefetch next r2's V frags (issued before this iteration's compute;
        // awaited only next iteration -> full compute-phase latency cover).
        if (r2 < 7) {
            #pragma unroll
            for (int nt = 0; nt < 2; ++nt)
                #pragma unroll
                for (int ks1 = 0; ks1 < 4; ++ks1)
                    vfb[nxt][nt][ks1] = Vp[(((r2 + 1) * 2 + nt) * 4 + ks1) * 64 + lane];
        }

        #pragma unroll
        for (int mt = 0; mt < 2; ++mt) {
            // U loads issue here; first use is after GEMM1 (4 chained MFMA)
            // + relayout (~200 cyc) -> L2 latency covered.
            bf16x8 uf[2][2];                                       // [mt2][ks2], kt = mt
            #pragma unroll
            for (int mt2 = 0; mt2 < 2; ++mt2)
                #pragma unroll
                for (int ks2 = 0; ks2 < 2; ++ks2)
                    uf[mt2][ks2] = Up[(((r2 * 2 + mt2) * 2 + mt) * 2 + ks2) * 64 + lane];

            #pragma unroll
            for (int nt = 0; nt < 2; ++nt) {
                // GEMM1: S tile (mt,nt) = X * V_{r2}
                f32x16 s = (f32x16)0.0f;
                #pragma unroll
                for (int ks1 = 0; ks1 < 4; ++ks1)
                    s = MFMA32(xa[mt][ks1], vfb[cur][nt][ks1], s);

                // D-layout (4-row groups / half-wave) -> B-frag (8-row groups):
                // (w0,w2)=swap(pk(d0,d1),pk(d4,d5)); (w1,w3)=swap(pk(d2,d3),pk(d6,d7)).
                bf16x8 bf[2];
                #pragma unroll
                for (int ks2 = 0; ks2 < 2; ++ks2) {
                    unsigned A0 = pk2(s[8 * ks2 + 0], s[8 * ks2 + 1]);
                    unsigned B0 = pk2(s[8 * ks2 + 2], s[8 * ks2 + 3]);
                    unsigned A1 = pk2(s[8 * ks2 + 4], s[8 * ks2 + 5]);
                    unsigned B1 = pk2(s[8 * ks2 + 6], s[8 * ks2 + 7]);
                    auto rA = __builtin_amdgcn_permlane32_swap((int)A0, (int)A1, false, false);
                    auto rB = __builtin_amdgcn_permlane32_swap((int)B0, (int)B1, false, false);
                    union { unsigned w[4]; bf16x8 v; } t;
                    t.w[0] = (unsigned)rA[0];
                    t.w[1] = (unsigned)rB[0];
                    t.w[2] = (unsigned)rA[1];
                    t.w[3] = (unsigned)rB[1];
                    bf[ks2] = t.v;
                }

                // GEMM2: Y[mt2][nt] += U^T frag (kt=mt) * S frag
                #pragma unroll
                for (int mt2 = 0; mt2 < 2; ++mt2)
                    #pragma unroll
                    for (int ks2 = 0; ks2 < 2; ++ks2)
                        yacc[mt2][nt] = MFMA32(uf[mt2][ks2], bf[ks2], yacc[mt2][nt]);
            }
        }
    }

    // Epilogue: D layout row = (r&3)+8*(r>>2)+4*hi (+32*mt2), col = l31 (+32*nt)
    float* ob = out + (size_t)b * 4096;
    #pragma unroll
    for (int mt2 = 0; mt2 < 2; ++mt2)
        #pragma unroll
        for (int nt = 0; nt < 2; ++nt)
            #pragma unroll
            for (int r = 0; r < 16; ++r) {
                int o01 = mt2 * 32 + (r & 3) + 8 * (r >> 2) + 4 * hi;
                int o23 = nt * 32 + l31;
                int off = o01 * 64 + o23;
                ob[off] = yacc[mt2][nt][r] + bias[off];
            }
}

extern "C" void kernel_launch(void* const* d_in, const int* in_sizes, int n_in,
                              void* d_out, int out_size, void* d_ws, size_t ws_size,
                              hipStream_t stream) {
    const float* x    = (const float*)d_in[0];
    const float* c0   = (const float*)d_in[1];
    const float* c1   = (const float*)d_in[2];
    const float* c2   = (const float*)d_in[3];
    const float* c3   = (const float*)d_in[4];
    const float* bias = (const float*)d_in[5];
    unsigned short* wpack = (unsigned short*)d_ws;                 // 64K bf16 = 128 KB

    tt_prep<<<256, 256, 0, stream>>>(c0, c1, c2, c3, wpack);
    tt_main<<<1024, 256, 0, stream>>>(x, bias, wpack, (float*)d_out);
}

// Round 9
// 145.053 us; speedup vs baseline: 1.1231x; 1.0213x over previous
//
#include <hip/hip_runtime.h>
#include <hip/hip_bf16.h>

// TT linear: y[b, o01*64+o23] = sum_{r2} (U_{r2}^T @ X_b @ V_{r2})[o01][o23]
// One wave per row. GEMM1 S = X*V_{r2}, in-register relayout via
// v_permlane32_swap, GEMM2 Y += U^T*S. Weights pre-packed in 32x32x16 MFMA
// fragment order; each block stages them into a 64 KB LDS buffer in two
// halves (r2 0-3, r2 4-7) via global_load_lds -> weight reads are ds_read_b128
// (lgkmcnt path, 256 B/cyc/CU) instead of per-wave L2 traffic (round-8's
// latency-serialized 512 MB). Only 3 barriers per kernel.

typedef __attribute__((ext_vector_type(8))) short bf16x8;    // 8 bf16 = 4 VGPRs
typedef __attribute__((ext_vector_type(16))) float f32x16;   // 32x32 MFMA acc

#define MFMA32(a, b, c) __builtin_amdgcn_mfma_f32_32x32x16_bf16(a, b, c, 0, 0, 0)

__device__ __forceinline__ unsigned short bfu(float f) {
    __hip_bfloat16 h = __float2bfloat16(f);                   // RNE
    return *reinterpret_cast<unsigned short*>(&h);
}
__device__ __forceinline__ unsigned pk2(float a, float b) {
    return (unsigned)bfu(a) | ((unsigned)bfu(b) << 16);
}

__device__ __forceinline__ void gload_lds16(const char* g, char* l) {
    __builtin_amdgcn_global_load_lds(
        (const __attribute__((address_space(1))) unsigned int*)g,
        (__attribute__((address_space(3))) unsigned int*)l,
        16, 0, 0);                                            // 16B/lane, wave-linear LDS dest
}

// ---------------------------------------------------------------------------
// Prep: contract cores, write bf16 packed in 32x32x16 MFMA fragment order.
// First 32768: V B-frags [r2][nt][ks1][lane][j]:  k=i23=ks1*16+(lane>>5)*8+j, n=o23=nt*32+(lane&31)
// Next  32768: U A-frags [r2][mt2][kt][ks2][lane][j]: k=i01=kt*32+ks2*16+(lane>>5)*8+j, m=o01=mt2*32+(lane&31)
// ---------------------------------------------------------------------------
__global__ void tt_prep(const float* __restrict__ c0, const float* __restrict__ c1,
                        const float* __restrict__ c2, const float* __restrict__ c3,
                        unsigned short* __restrict__ wpack) {
    int e    = blockIdx.x * 256 + threadIdx.x;                // 0..65535
    int lane = (e >> 3) & 63;
    int j    = e & 7;
    int hi   = lane >> 5, l31 = lane & 31;
    float acc = 0.f;
    if (e < 32768) {
        int idx = e;
        int r2  = idx >> 12;
        int nt  = (idx >> 11) & 1;
        int ks1 = (idx >> 9) & 3;
        int i23 = ks1 * 16 + hi * 8 + j;
        int o23 = nt * 32 + l31;
        int i2 = i23 >> 3, i3 = i23 & 7, o2 = o23 >> 3, o3 = o23 & 7;
        #pragma unroll
        for (int r3 = 0; r3 < 8; ++r3)
            acc += c2[((r2 * 8 + i2) * 8 + o2) * 8 + r3] * c3[(r3 * 8 + i3) * 8 + o3];
    } else {
        int idx = e - 32768;
        int r2  = idx >> 12;
        int mt2 = (idx >> 11) & 1;
        int kt  = (idx >> 10) & 1;
        int ks2 = (idx >> 9) & 1;
        int i01 = kt * 32 + ks2 * 16 + hi * 8 + j;
        int o01 = mt2 * 32 + l31;
        int i0 = i01 >> 3, i1 = i01 & 7, o0 = o01 >> 3, o1 = o01 & 7;
        #pragma unroll
        for (int r1 = 0; r1 < 8; ++r1)
            acc += c0[(i0 * 8 + o0) * 8 + r1] * c1[((r1 * 8 + i1) * 8 + o1) * 8 + r2];
    }
    wpack[e] = bfu(acc);
}

// ---------------------------------------------------------------------------
// Stage one half (4 r2 values, 64 KB: V 32 KB -> LDS [0,32K), U 32 KB ->
// LDS [32K,64K)). 8 sweeps x 512 thr x 16 B. LDS dest is wave-linear.
// ---------------------------------------------------------------------------
__device__ __forceinline__ void stage_half(const char* wp, char* sm, int h,
                                           int wave, int lane) {
    #pragma unroll
    for (int i = 0; i < 8; ++i) {
        int isU = i >> 2;
        const char* src = wp + isU * 65536 + h * 32768 + (i & 3) * 8192
                          + wave * 1024 + lane * 16;
        char* dst = sm + i * 8192 + wave * 1024;              // wave-uniform base
        gload_lds16(src, dst);
    }
}

// ---------------------------------------------------------------------------
// Main: 512 blocks x 512 threads (8 waves). Wave w of block g: row b = g*8+w.
// ---------------------------------------------------------------------------
__global__ __launch_bounds__(512, 2)
void tt_main(const float* __restrict__ x, const float* __restrict__ bias,
             const unsigned short* __restrict__ wpack, float* __restrict__ out) {
    __shared__ __attribute__((aligned(16))) char smem[65536];
    const int lane = threadIdx.x & 63;
    const int wave = threadIdx.x >> 6;
    const int b    = blockIdx.x * 8 + wave;
    const int l31  = lane & 31;
    const int hi   = lane >> 5;
    const char* wp = (const char*)wpack;

    stage_half(wp, smem, 0, wave, lane);                      // stage r2 0-3

    // ---- x A-frags: xa[mt][ks1], a[j] = x[i01=mt*32+l31][i23=ks1*16+hi*8+j] ----
    const float* xb = x + (size_t)b * 4096;
    bf16x8 xa[2][4];
    #pragma unroll
    for (int mt = 0; mt < 2; ++mt)
        #pragma unroll
        for (int ks1 = 0; ks1 < 4; ++ks1) {
            const float* p = xb + (mt * 32 + l31) * 64 + ks1 * 16 + hi * 8;
            float4 u0 = *(const float4*)p;
            float4 u1 = *(const float4*)(p + 4);
            union { unsigned w[4]; bf16x8 v; } t;
            t.w[0] = pk2(u0.x, u0.y);
            t.w[1] = pk2(u0.z, u0.w);
            t.w[2] = pk2(u1.x, u1.y);
            t.w[3] = pk2(u1.z, u1.w);
            xa[mt][ks1] = t.v;
        }

    f32x16 yacc[2][2];
    #pragma unroll
    for (int i = 0; i < 2; ++i)
        #pragma unroll
        for (int k = 0; k < 2; ++k)
            yacc[i][k] = (f32x16)0.0f;

    __syncthreads();                                          // half 0 staged

    const char* VL = smem;                                    // V frag f: f*1024+lane*16
    const char* UL = smem + 32768;                            // U frag g: g*1024+lane*16

    #pragma unroll
    for (int h = 0; h < 2; ++h) {
        if (h == 1) {
            __syncthreads();                                  // all waves done with half 0
            stage_half(wp, smem, 1, wave, lane);              // stage r2 4-7
            __syncthreads();                                  // half 1 staged
        }
        #pragma unroll
        for (int r2h = 0; r2h < 4; ++r2h) {
            #pragma unroll
            for (int mt = 0; mt < 2; ++mt) {
                bf16x8 uf[2][2];                              // [mt2][ks2], kt = mt
                #pragma unroll
                for (int mt2 = 0; mt2 < 2; ++mt2)
                    #pragma unroll
                    for (int ks2 = 0; ks2 < 2; ++ks2)
                        uf[mt2][ks2] = *(const bf16x8*)(UL +
                            ((((r2h * 2 + mt2) * 2 + mt) * 2 + ks2) << 10) + lane * 16);

                #pragma unroll
                for (int nt = 0; nt < 2; ++nt) {
                    // GEMM1: S tile (mt,nt) = X * V_{r2}
                    f32x16 s = (f32x16)0.0f;
                    #pragma unroll
                    for (int ks1 = 0; ks1 < 4; ++ks1)
                        s = MFMA32(xa[mt][ks1],
                                   *(const bf16x8*)(VL +
                                       (((r2h * 2 + nt) * 4 + ks1) << 10) + lane * 16),
                                   s);

                    // D-layout (4-row groups / half-wave) -> B-frag (8-row groups):
                    // (w0,w2)=swap(pk(d0,d1),pk(d4,d5)); (w1,w3)=swap(pk(d2,d3),pk(d6,d7)).
                    bf16x8 bf[2];
                    #pragma unroll
                    for (int ks2 = 0; ks2 < 2; ++ks2) {
                        unsigned A0 = pk2(s[8 * ks2 + 0], s[8 * ks2 + 1]);
                        unsigned B0 = pk2(s[8 * ks2 + 2], s[8 * ks2 + 3]);
                        unsigned A1 = pk2(s[8 * ks2 + 4], s[8 * ks2 + 5]);
                        unsigned B1 = pk2(s[8 * ks2 + 6], s[8 * ks2 + 7]);
                        auto rA = __builtin_amdgcn_permlane32_swap((int)A0, (int)A1, false, false);
                        auto rB = __builtin_amdgcn_permlane32_swap((int)B0, (int)B1, false, false);
                        union { unsigned w[4]; bf16x8 v; } t;
                        t.w[0] = (unsigned)rA[0];
                        t.w[1] = (unsigned)rB[0];
                        t.w[2] = (unsigned)rA[1];
                        t.w[3] = (unsigned)rB[1];
                        bf[ks2] = t.v;
                    }

                    // GEMM2: Y[mt2][nt] += U^T frag (kt=mt) * S frag
                    #pragma unroll
                    for (int mt2 = 0; mt2 < 2; ++mt2)
                        #pragma unroll
                        for (int ks2 = 0; ks2 < 2; ++ks2)
                            yacc[mt2][nt] = MFMA32(uf[mt2][ks2], bf[ks2], yacc[mt2][nt]);
                }
            }
        }
    }

    // Epilogue: D layout row = (r&3)+8*(r>>2)+4*hi (+32*mt2), col = l31 (+32*nt)
    float* ob = out + (size_t)b * 4096;
    #pragma unroll
    for (int mt2 = 0; mt2 < 2; ++mt2)
        #pragma unroll
        for (int nt = 0; nt < 2; ++nt)
            #pragma unroll
            for (int r = 0; r < 16; ++r) {
                int o01 = mt2 * 32 + (r & 3) + 8 * (r >> 2) + 4 * hi;
                int o23 = nt * 32 + l31;
                int off = o01 * 64 + o23;
                ob[off] = yacc[mt2][nt][r] + bias[off];
            }
}

extern "C" void kernel_launch(void* const* d_in, const int* in_sizes, int n_in,
                              void* d_out, int out_size, void* d_ws, size_t ws_size,
                              hipStream_t stream) {
    const float* x    = (const float*)d_in[0];
    const float* c0   = (const float*)d_in[1];
    const float* c1   = (const float*)d_in[2];
    const float* c2   = (const float*)d_in[3];
    const float* c3   = (const float*)d_in[4];
    const float* bias = (const float*)d_in[5];
    unsigned short* wpack = (unsigned short*)d_ws;             // 64K bf16 = 128 KB

    tt_prep<<<256, 256, 0, stream>>>(c0, c1, c2, c3, wpack);
    tt_main<<<512, 512, 0, stream>>>(x, bias, wpack, (float*)d_out);
}